// Round 19
// baseline (263.712 us; speedup 1.0000x reference)
//
#include <hip/hip_runtime.h>
#include <math.h>

// feat_arm/feat_up: [16,144,64,64] f32
// off_w: [144,288,3,3], off_b: [144]
// dcn_w: [256,144,3,3], dcn_b: [256]
// out: [16,256,64,64] f32 (silu)
constexpr int BN = 16;
constexpr int C_IN = 144, C_CAT = 288, C_OFF = 144, C_OUT = 256;
constexpr int OFFG = 8, CG = 18;

constexpr int FUB_ELEMS  = C_IN * BN * 4096;      // 9,437,184 f16 planar feat_up
constexpr int OFFP_ELEMS = BN * 72 * 4096;        // 4,718,592 u32 fp16 offset pairs
constexpr int WOFF_PACK = 9 * 9 * 9 * 512;        // bf16 (cb,tap,mtile,lane,i)
constexpr int WDCN_PACK = 8 * 6 * 16 * 512;       // f16  (t=g*6+ks, mtile, lane, i)

typedef __attribute__((ext_vector_type(8))) short bf16x8;
typedef __attribute__((ext_vector_type(8))) _Float16 f16x8;
typedef __attribute__((ext_vector_type(2))) _Float16 f16x2;
typedef __attribute__((ext_vector_type(4))) float f32x4;
typedef __attribute__((ext_vector_type(4))) unsigned u32x4;

__device__ __forceinline__ unsigned short f2bf(float f) {
  unsigned u = __builtin_bit_cast(unsigned, f);
  return (unsigned short)((u + 0x7FFFu + ((u >> 16) & 1u)) >> 16);  // RNE, finite inputs
}

__device__ __forceinline__ unsigned packh2(float a, float b) {
  unsigned short ha = __builtin_bit_cast(unsigned short, (_Float16)a);
  unsigned short hb = __builtin_bit_cast(unsigned short, (_Float16)b);
  return (unsigned)ha | ((unsigned)hb << 16);
}
__device__ __forceinline__ float h2f_lo(unsigned u) {
  return (float)__builtin_bit_cast(_Float16, (unsigned short)(u & 0xFFFFu));
}
__device__ __forceinline__ float h2f_hi(unsigned u) {
  return (float)__builtin_bit_cast(_Float16, (unsigned short)(u >> 16));
}

// async global->LDS, 16B per lane, wave-uniform LDS base
__device__ __forceinline__ void gload_lds16(const void* g, void* l) {
  __builtin_amdgcn_global_load_lds(
      (const __attribute__((address_space(1))) unsigned*)g,
      (__attribute__((address_space(3))) unsigned*)l, 16, 0, 0);
}

// ---------------------------------------------------------------------------
// Kernel 1: prep — weight packs only (fuB is now produced by offs_conv).
// ---------------------------------------------------------------------------
__global__ __launch_bounds__(256) void prep(
    const float* __restrict__ off_w, const float* __restrict__ dcn_w,
    unsigned short* __restrict__ wo, _Float16* __restrict__ wd) {
  int idx = blockIdx.x * 256 + threadIdx.x;
  if (idx < WOFF_PACK) {
    int i = idx & 7, lane = (idx >> 3) & 63, t = idx >> 9;
    int mt = t % 9; t /= 9;
    int tap = t % 9, cb = t / 9;
    int co = mt * 16 + (lane & 15);
    int ci = cb * 32 + ((lane >> 4) << 3) + i;
    wo[idx] = f2bf(off_w[(co * C_CAT + ci) * 9 + tap]);
  }
  if (idx < WDCN_PACK) {
    int i = idx & 7, lane = (idx >> 3) & 63, t = idx >> 9;
    int mt = t & 15; t >>= 4;
    int ks = t % 6, g = t / 6;
    int co = mt * 16 + (lane & 15);
    int r = ks * 32 + ((lane >> 4) << 3) + i;
    float v = 0.f;
    if (r < 162) {
      int ci = r / 9, tap = r - ci * 9;
      v = dcn_w[(co * C_IN + g * CG + ci) * 9 + tap];
    }
    wd[idx] = (_Float16)v;
  }
}

// ---------------------------------------------------------------------------
// Kernel 2: offset conv via MFMA (r18-proven: XCD swizzle + setprio).
// NEW: the xs staging loop also emits fuB (planar f16 feat_up) for the two
// interior rows it owns (rows 1,2 of the 4-row window, fu channels only) —
// every (b,y) pair is owned by exactly one block, so coverage is complete.
// ---------------------------------------------------------------------------
__global__ __launch_bounds__(256) void offs_conv_mfma(
    const float* __restrict__ fa, const float* __restrict__ fu,
    const unsigned short* __restrict__ wt, const float* __restrict__ bias,
    unsigned* __restrict__ offp, _Float16* __restrict__ fuB) {
  const int bid = (blockIdx.x & 7) * 64 + (blockIdx.x >> 3);  // XCD swizzle
  const int b = bid >> 5;
  const int y0 = (bid & 31) << 1;
  const int tid = threadIdx.x;
  const int wave = tid >> 6, lane = tid & 63;
  const int kg = lane >> 4, ln = lane & 15;

  __shared__ __align__(16) unsigned short xs[4 * 66 * 32];

  f32x4 acc[9][2];
#pragma unroll
  for (int m = 0; m < 9; ++m)
#pragma unroll
    for (int n = 0; n < 2; ++n) acc[m][n] = {0.f, 0.f, 0.f, 0.f};

  for (int cb = 0; cb < 9; ++cb) {
    __syncthreads();
    for (int idx = tid; idx < 2112; idx += 256) {
      int q = idx / 264;
      int rem = idx - q * 264;
      int row = rem / 66;
      int cc = rem - row * 66;
      int y = y0 - 1 + row, x = cc - 1;
      ushort4 wv = make_ushort4(0, 0, 0, 0);
      if (y >= 0 && y < 64 && x >= 0 && x < 64) {
        int cib = cb * 32 + (q << 2);
        const float* p = (cib < C_IN)
                             ? fa + (((size_t)(b * C_IN + cib)) << 12)
                             : fu + (((size_t)(b * C_IN + cib - C_IN)) << 12);
        int o = (y << 6) + x;
        float v0 = p[o], v1 = p[o + 4096], v2 = p[o + 8192], v3 = p[o + 12288];
        wv.x = f2bf(v0);
        wv.y = f2bf(v1);
        wv.z = f2bf(v2);
        wv.w = f2bf(v3);
        // emit fuB for interior rows (y ∈ {y0, y0+1}) of fu channels
        if (cib >= C_IN && row >= 1 && row <= 2) {
          _Float16* fb = fuB + (((size_t)(b * C_IN + cib - C_IN)) << 12) + o;
          fb[0] = (_Float16)v0;
          fb[4096] = (_Float16)v1;
          fb[8192] = (_Float16)v2;
          fb[12288] = (_Float16)v3;
        }
      }
      int e = ((row * 66 + cc) << 5) + (((q >> 1) ^ (cc & 3)) << 3) + ((q & 1) << 2);
      *(ushort4*)&xs[e] = wv;
    }
    __syncthreads();

    for (int tap = 0; tap < 9; ++tap) {
      const int ky = tap / 3, kx = tap - ky * 3;
      bf16x8 a[9];
      const unsigned short* wp = wt + (((size_t)(cb * 9 + tap) * 9) << 9) + (lane << 3);
#pragma unroll
      for (int m = 0; m < 9; ++m) a[m] = *(const bf16x8*)(wp + (m << 9));
#pragma unroll
      for (int n = 0; n < 2; ++n) {
        int px = ((wave << 1) + n) * 16 + ln;
        int row = (px >> 6) + ky, cc = (px & 63) + kx;
        int e = ((row * 66 + cc) << 5) + ((kg ^ (cc & 3)) << 3);
        bf16x8 bv = *(const bf16x8*)&xs[e];
        __builtin_amdgcn_s_setprio(1);
#pragma unroll
        for (int m = 0; m < 9; ++m)
          acc[m][n] = __builtin_amdgcn_mfma_f32_16x16x32_bf16(a[m], bv, acc[m][n], 0, 0, 0);
        __builtin_amdgcn_s_setprio(0);
      }
    }
  }

  // epilogue: C/D col=lane&15 (px), row=(lane>>4)*4+r (co); pack pairs fp16
#pragma unroll
  for (int n = 0; n < 2; ++n) {
    int px = ((wave << 1) + n) * 16 + ln;
    int y = y0 + (px >> 6), x = px & 63;
#pragma unroll
    for (int m = 0; m < 9; ++m) {
      int cob = m * 16 + (kg << 2);
#pragma unroll
      for (int rr = 0; rr < 4; rr += 2) {
        unsigned v = packh2(acc[m][n][rr] + bias[cob + rr],
                            acc[m][n][rr + 1] + bias[cob + rr + 1]);
        offp[(((size_t)(b * 72 + ((cob + rr) >> 1))) << 12) + (y << 6) + x] = v;
      }
    }
  }
}

// ---------------------------------------------------------------------------
// Kernel 3: deformable conv via MFMA. r18 skeleton + CROSS-GROUP GATHER
// PIPELINE: gather loads for group g+1 are issued inside group g's phase 3
// (after ks=0's MFMA cluster), held in statically-indexed registers, and
// consumed by a pure-VALU phase-2' at the top of group g+1 — the gather
// latency hides under 5 K-steps of MFMA instead of being exposed.
// vmcnt bookkeeping (in-order counter, m135): gathers are UNIFORM 42/wave
// (waves 2-7 pad with clamped dup loads); stage@ks0 is issued BEFORE the
// gathers (the ks0 vmcnt asm fences the order), so ks=1 uses vmcnt(44)
// (= 42 gathers + 2 stage@ks1); ks>=2 reverts to vmcnt(2) which forces
// gathers complete with >=1 K-step (~2.5K cyc) of cover.
// ---------------------------------------------------------------------------
__global__ __launch_bounds__(512, 4) void dcn_mfma(
    const _Float16* __restrict__ fuB, const unsigned* __restrict__ offp,
    const _Float16* __restrict__ wt, const float* __restrict__ bias,
    float* __restrict__ out) {
  const int bid = (blockIdx.x & 7) * 128 + (blockIdx.x >> 3);  // XCD swizzle
  const int b = bid >> 6, h = bid & 63;
  const int tid = threadIdx.x;
  const int wave = tid >> 6, lane = tid & 63;
  const int kg = lane >> 4, ln = lane & 15;
  const int wm = wave >> 2, wn = wave & 3;   // M-half, N-tile
  const int px = (wn << 4) + ln;             // this wave's pixel (n index)
  const int n8 = (wave < 2) ? 3 : 2;         // real tap-8 rows for this wave

  __shared__ __align__(16) unsigned short colsT[64 * 202];// [px][r pad 202], f16
  __shared__ __align__(16) _Float16 wl[3][8192];          // A tri-buf, 3x16KB

  f32x4 acc[8];
#pragma unroll
  for (int m = 0; m < 8; ++m) acc[m] = {0.f, 0.f, 0.f, 0.f};

  // zero K-pad region r in [162,192) once (15 u32 per px) — MFMA-safe pad
  for (int i = tid; i < 64 * 15; i += 512) {
    int p = i / 15, d = i - p * 15;
    *(unsigned*)&colsT[p * 202 + 162 + 2 * d] = 0u;
  }

  // prologue: stage A chunk t=0 into buffer 0 (16 rows of 1KB, 2 per wave)
  {
    const _Float16* src = wt + (wave * 2) * 512 + lane * 8;
#pragma unroll
    for (int j = 0; j < 2; ++j)
      gload_lds16(src + j * 512, &wl[0][(wave * 2 + j) * 512]);
  }

  // geometry for (group, tap, pixel p), x-corner-pair folded (r11-proven):
  auto make_geo = [&](int gg_, int tap, int p) -> uint4 {
    int ky = tap / 3, kx = tap - ky * 3;
    unsigned op = offp[(((size_t)(b * 72 + gg_ * 9 + tap)) << 12) + (h << 6) + p];
    float oy = h2f_lo(op), ox = h2f_hi(op);
    float py = (float)(h - 1 + ky) + oy;
    float pxs = (float)(p - 1 + kx) + ox;
    float y0f = floorf(py), x0f = floorf(pxs);
    int y0 = (int)y0f, x0 = (int)x0f;
    float fy = py - y0f, fx = pxs - x0f;
    float vy0 = (y0 >= 0 && y0 < 64) ? 1.f : 0.f;
    float vy1 = (y0 + 1 >= 0 && y0 + 1 < 64) ? 1.f : 0.f;
    float vx0 = (x0 >= 0 && x0 < 64) ? 1.f : 0.f;
    float vx1 = (x0 + 1 >= 0 && x0 + 1 < 64) ? 1.f : 0.f;
    float a0 = (1.f - fx) * vx0;
    float a1 = fx * vx1;
    float wlo = (x0 == -1) ? a1 : (x0 == 63 ? 0.f : a0);
    float whi = (x0 == 63) ? a0 : (x0 == -1 ? 0.f : a1);
    int xL = min(max(x0, 0), 62);
    int yc0 = min(max(y0, 0), 63), yc1 = min(max(y0 + 1, 0), 63);
    float cy0 = (1.f - fy) * vy0, cy1 = fy * vy1;
    uint4 r;
    r.x = (unsigned)((yc0 << 6) + xL) | ((unsigned)((yc1 << 6) + xL) << 16);
    r.y = 0u;
    r.z = packh2(cy0 * wlo, cy0 * whi);
    r.w = packh2(cy1 * wlo, cy1 * whi);
    return r;
  };

  // persistent gather state (statically indexed — rule #20)
  unsigned d0[18], d1[18], e0[3], e1[3];
  unsigned wz_cur, ww_cur, uz_cur, uw_cur;  // current group's geo weights

  // prologue: geo(0) + issue gathers(0). UNIFORM 42 loads per wave.
  {
    uint4 g0 = make_geo(0, wave, lane);
    uint4 g80 = make_geo(0, 8, lane);
    wz_cur = g0.z; ww_cur = g0.w; uz_cur = g80.z; uw_cur = g80.w;
    const _Float16* gb = fuB + ((size_t)(b * C_IN) << 12);
    const int iL0 = g0.x & 0xFFFFu, iL1 = g0.x >> 16;
    const int j0 = g80.x & 0xFFFFu, j1 = g80.x >> 16;
#pragma unroll
    for (int u = 0; u < 18; ++u) {
      const _Float16* pl = gb + ((size_t)u << 12);
      __builtin_memcpy(&d0[u], pl + iL0, 4);
      __builtin_memcpy(&d1[u], pl + iL1, 4);
    }
#pragma unroll
    for (int u = 0; u < 3; ++u) {
      int ci8 = min(wave + 8 * u, CG - 1);  // waves 2-7 u=2: clamped dup
      const _Float16* pl = gb + ((size_t)ci8 << 12);
      __builtin_memcpy(&e0[u], pl + j0, 4);
      __builtin_memcpy(&e1[u], pl + j1, 4);
    }
  }

  int tg = 0, cur = 0;  // global K-step, tri-buffer index (cur == tg % 3)
  for (int g = 0; g < OFFG; ++g) {
    __syncthreads();  // prev group's colsT readers done

    // ---- phase 2': compute samples from REGISTERS, write colsT (no loads)
    {
      const f16x2 w0 = __builtin_bit_cast(f16x2, wz_cur);
      const f16x2 w1 = __builtin_bit_cast(f16x2, ww_cur);
      const f16x2 u0 = __builtin_bit_cast(f16x2, uz_cur);
      const f16x2 u1 = __builtin_bit_cast(f16x2, uw_cur);
#pragma unroll
      for (int u = 0; u < 18; ++u) {
        f16x2 sp = __builtin_bit_cast(f16x2, d0[u]) * w0 +
                   __builtin_bit_cast(f16x2, d1[u]) * w1;
        _Float16 s = sp[0] + sp[1];
        colsT[lane * 202 + u * 9 + wave] = __builtin_bit_cast(unsigned short, s);
      }
#pragma unroll
      for (int u = 0; u < 3; ++u) {
        if (u < n8) {
          f16x2 sp = __builtin_bit_cast(f16x2, e0[u]) * u0 +
                     __builtin_bit_cast(f16x2, e1[u]) * u1;
          _Float16 s = sp[0] + sp[1];
          colsT[lane * 202 + (wave + 8 * u) * 9 + 8] =
              __builtin_bit_cast(unsigned short, s);
        }
      }
    }
    __syncthreads();  // colsT ready

    // ---- phase 3: 6 MFMA K-steps; counted-vmcnt tri-buffer staging (T4)
    for (int ks = 0; ks < 6; ++ks, ++tg) {
      // B fragment: 4 x ds_read_b32 (odd-dword row stride, conflict-free)
      int cbase = px * 202 + ks * 32 + (kg << 3);
      u32x4 bu;
      bu[0] = *(const unsigned*)&colsT[cbase];
      bu[1] = *(const unsigned*)&colsT[cbase + 2];
      bu[2] = *(const unsigned*)&colsT[cbase + 4];
      bu[3] = *(const unsigned*)&colsT[cbase + 6];
      f16x8 bv = __builtin_bit_cast(f16x8, bu);

      int nxt = cur + 1;
      if (nxt == 3) nxt = 0;
      if (tg < 47) {
        const _Float16* src =
            wt + (size_t)(tg + 1) * 8192 + (wave * 2) * 512 + lane * 8;
        _Float16* dst = wl[nxt];
#pragma unroll
        for (int j = 0; j < 2; ++j)
          gload_lds16(src + j * 512, dst + (wave * 2 + j) * 512);
        // ks==1 with gathers(g+1) in flight (issued at ks==0, g<7):
        // stage@ks0 done <=> outstanding <= 42 gathers + 2 stage@ks1 = 44.
        if (ks == 1 && g < 7) {
          asm volatile("s_waitcnt vmcnt(44)" ::: "memory");
        } else {
          asm volatile("s_waitcnt vmcnt(2)" ::: "memory");
        }
      } else {
        asm volatile("s_waitcnt vmcnt(0)" ::: "memory");
      }
      __builtin_amdgcn_s_barrier();

      // 8 MFMAs: this wave's M-half against its B fragment (T5 setprio)
      const _Float16* wbuf = wl[cur] + (wm * 8) * 512 + lane * 8;
      __builtin_amdgcn_s_setprio(1);
#pragma unroll
      for (int j = 0; j < 8; ++j) {
        f16x8 av = *(const f16x8*)(wbuf + j * 512);
        acc[j] = __builtin_amdgcn_mfma_f32_16x16x32_f16(av, bv, acc[j], 0, 0, 0);
      }
      __builtin_amdgcn_s_setprio(0);
      cur = nxt;

      // ---- cross-group gather: geo(g+1) + issue 42 uniform loads.
      // Placed AFTER ks0's MFMA cluster; ks0's vmcnt asm above fences the
      // issue order (stage@ks0 < vmcnt < gathers).
      if (ks == 0 && g < 7) {
        uint4 gn = make_geo(g + 1, wave, lane);
        uint4 g8n = make_geo(g + 1, 8, lane);
        wz_cur = gn.z; ww_cur = gn.w; uz_cur = g8n.z; uw_cur = g8n.w;
        const _Float16* gbn = fuB + (((size_t)(b * C_IN + (g + 1) * CG)) << 12);
        const int iL0 = gn.x & 0xFFFFu, iL1 = gn.x >> 16;
        const int j0 = g8n.x & 0xFFFFu, j1 = g8n.x >> 16;
#pragma unroll
        for (int u = 0; u < 18; ++u) {
          const _Float16* pl = gbn + ((size_t)u << 12);
          __builtin_memcpy(&d0[u], pl + iL0, 4);
          __builtin_memcpy(&d1[u], pl + iL1, 4);
        }
#pragma unroll
        for (int u = 0; u < 3; ++u) {
          int ci8 = min(wave + 8 * u, CG - 1);
          const _Float16* pl = gbn + ((size_t)ci8 << 12);
          __builtin_memcpy(&e0[u], pl + j0, 4);
          __builtin_memcpy(&e1[u], pl + j1, 4);
        }
      }
    }
  }

  // ---- epilogue: bias + SiLU.  C/D: col(px)=lane&15, row=kg*4+r
#pragma unroll
  for (int j = 0; j < 8; ++j) {
    int cob = (wm * 8 + j) * 16 + (kg << 2);
#pragma unroll
    for (int r = 0; r < 4; ++r) {
      float y = acc[j][r] + bias[cob + r];
      out[(((size_t)(b * C_OUT + cob + r)) << 12) + (h << 6) + px] =
          y / (1.f + expf(-y));
    }
  }
}

// ---------------------------------------------------------------------------
extern "C" void kernel_launch(void* const* d_in, const int* in_sizes, int n_in,
                              void* d_out, int out_size, void* d_ws, size_t ws_size,
                              hipStream_t stream) {
  const float* feat_arm = (const float*)d_in[0];
  const float* feat_up  = (const float*)d_in[1];
  const float* off_w    = (const float*)d_in[2];
  const float* off_b    = (const float*)d_in[3];
  const float* dcn_w    = (const float*)d_in[4];
  const float* dcn_b    = (const float*)d_in[5];
  float* out = (float*)d_out;

  // ws layout (identical sizes to rounds 12-18):
  _Float16* fuB = (_Float16*)d_ws;                        // FUB_ELEMS f16
  unsigned* offp = (unsigned*)(fuB + FUB_ELEMS);          // OFFP_ELEMS u32
  unsigned short* wo = (unsigned short*)(offp + OFFP_ELEMS);
  _Float16* wd = (_Float16*)(wo + WOFF_PACK);

  prep<<<(WDCN_PACK + 255) / 256, 256, 0, stream>>>(off_w, dcn_w, wo, wd);
  offs_conv_mfma<<<BN * 32, 256, 0, stream>>>(feat_arm, feat_up, wo, off_b, offp, fuB);
  dcn_mfma<<<BN * 64, 512, 0, stream>>>(fuB, offp, wd, dcn_b, out);
}

// Round 20
// 248.382 us; speedup vs baseline: 1.0617x; 1.0617x over previous
//
#include <hip/hip_runtime.h>
#include <math.h>

// feat_arm/feat_up: [16,144,64,64] f32
// off_w: [144,288,3,3], off_b: [144]
// dcn_w: [256,144,3,3], dcn_b: [256]
// out: [16,256,64,64] f32 (silu)
constexpr int BN = 16;
constexpr int C_IN = 144, C_CAT = 288, C_OFF = 144, C_OUT = 256;
constexpr int OFFG = 8, CG = 18;

constexpr int FUB_ELEMS  = C_IN * BN * 4096;      // 9,437,184 f16 planar feat_up
constexpr int OFFP_ELEMS = BN * 72 * 4096;        // 4,718,592 u32 fp16 offset pairs
constexpr int WOFF_PACK = 9 * 9 * 9 * 512;        // bf16 (cb,tap,mtile,lane,i)
constexpr int WDCN_PACK = 8 * 6 * 16 * 512;       // f16  (t=g*6+ks, mtile, lane, i)

typedef __attribute__((ext_vector_type(8))) short bf16x8;
typedef __attribute__((ext_vector_type(8))) _Float16 f16x8;
typedef __attribute__((ext_vector_type(2))) _Float16 f16x2;
typedef __attribute__((ext_vector_type(4))) float f32x4;
typedef __attribute__((ext_vector_type(4))) unsigned u32x4;

__device__ __forceinline__ unsigned short f2bf(float f) {
  unsigned u = __builtin_bit_cast(unsigned, f);
  return (unsigned short)((u + 0x7FFFu + ((u >> 16) & 1u)) >> 16);  // RNE, finite inputs
}

__device__ __forceinline__ unsigned packh2(float a, float b) {
  unsigned short ha = __builtin_bit_cast(unsigned short, (_Float16)a);
  unsigned short hb = __builtin_bit_cast(unsigned short, (_Float16)b);
  return (unsigned)ha | ((unsigned)hb << 16);
}
__device__ __forceinline__ float h2f_lo(unsigned u) {
  return (float)__builtin_bit_cast(_Float16, (unsigned short)(u & 0xFFFFu));
}
__device__ __forceinline__ float h2f_hi(unsigned u) {
  return (float)__builtin_bit_cast(_Float16, (unsigned short)(u >> 16));
}

// async global->LDS, 16B per lane, wave-uniform LDS base
__device__ __forceinline__ void gload_lds16(const void* g, void* l) {
  __builtin_amdgcn_global_load_lds(
      (const __attribute__((address_space(1))) unsigned*)g,
      (__attribute__((address_space(3))) unsigned*)l, 16, 0, 0);
}

// ---------------------------------------------------------------------------
// Kernel 1: prep — weight packs only (fuB produced by offs_conv).
// ---------------------------------------------------------------------------
__global__ __launch_bounds__(256) void prep(
    const float* __restrict__ off_w, const float* __restrict__ dcn_w,
    unsigned short* __restrict__ wo, _Float16* __restrict__ wd) {
  int idx = blockIdx.x * 256 + threadIdx.x;
  if (idx < WOFF_PACK) {
    int i = idx & 7, lane = (idx >> 3) & 63, t = idx >> 9;
    int mt = t % 9; t /= 9;
    int tap = t % 9, cb = t / 9;
    int co = mt * 16 + (lane & 15);
    int ci = cb * 32 + ((lane >> 4) << 3) + i;
    wo[idx] = f2bf(off_w[(co * C_CAT + ci) * 9 + tap]);
  }
  if (idx < WDCN_PACK) {
    int i = idx & 7, lane = (idx >> 3) & 63, t = idx >> 9;
    int mt = t & 15; t >>= 4;
    int ks = t % 6, g = t / 6;
    int co = mt * 16 + (lane & 15);
    int r = ks * 32 + ((lane >> 4) << 3) + i;
    float v = 0.f;
    if (r < 162) {
      int ci = r / 9, tap = r - ci * 9;
      v = dcn_w[(co * C_IN + g * CG + ci) * 9 + tap];
    }
    wd[idx] = (_Float16)v;
  }
}

// ---------------------------------------------------------------------------
// Kernel 2: offset conv via MFMA (r19-proven: XCD swizzle + setprio + fuB
// emission). The xs staging loop also emits fuB (planar f16 feat_up) for the
// two interior rows it owns — every (b,y) is owned by exactly one block.
// ---------------------------------------------------------------------------
__global__ __launch_bounds__(256) void offs_conv_mfma(
    const float* __restrict__ fa, const float* __restrict__ fu,
    const unsigned short* __restrict__ wt, const float* __restrict__ bias,
    unsigned* __restrict__ offp, _Float16* __restrict__ fuB) {
  const int bid = (blockIdx.x & 7) * 64 + (blockIdx.x >> 3);  // XCD swizzle
  const int b = bid >> 5;
  const int y0 = (bid & 31) << 1;
  const int tid = threadIdx.x;
  const int wave = tid >> 6, lane = tid & 63;
  const int kg = lane >> 4, ln = lane & 15;

  __shared__ __align__(16) unsigned short xs[4 * 66 * 32];

  f32x4 acc[9][2];
#pragma unroll
  for (int m = 0; m < 9; ++m)
#pragma unroll
    for (int n = 0; n < 2; ++n) acc[m][n] = {0.f, 0.f, 0.f, 0.f};

  for (int cb = 0; cb < 9; ++cb) {
    __syncthreads();
    for (int idx = tid; idx < 2112; idx += 256) {
      int q = idx / 264;
      int rem = idx - q * 264;
      int row = rem / 66;
      int cc = rem - row * 66;
      int y = y0 - 1 + row, x = cc - 1;
      ushort4 wv = make_ushort4(0, 0, 0, 0);
      if (y >= 0 && y < 64 && x >= 0 && x < 64) {
        int cib = cb * 32 + (q << 2);
        const float* p = (cib < C_IN)
                             ? fa + (((size_t)(b * C_IN + cib)) << 12)
                             : fu + (((size_t)(b * C_IN + cib - C_IN)) << 12);
        int o = (y << 6) + x;
        float v0 = p[o], v1 = p[o + 4096], v2 = p[o + 8192], v3 = p[o + 12288];
        wv.x = f2bf(v0);
        wv.y = f2bf(v1);
        wv.z = f2bf(v2);
        wv.w = f2bf(v3);
        // emit fuB for interior rows (y ∈ {y0, y0+1}) of fu channels
        if (cib >= C_IN && row >= 1 && row <= 2) {
          _Float16* fb = fuB + (((size_t)(b * C_IN + cib - C_IN)) << 12) + o;
          fb[0] = (_Float16)v0;
          fb[4096] = (_Float16)v1;
          fb[8192] = (_Float16)v2;
          fb[12288] = (_Float16)v3;
        }
      }
      int e = ((row * 66 + cc) << 5) + (((q >> 1) ^ (cc & 3)) << 3) + ((q & 1) << 2);
      *(ushort4*)&xs[e] = wv;
    }
    __syncthreads();

    for (int tap = 0; tap < 9; ++tap) {
      const int ky = tap / 3, kx = tap - ky * 3;
      bf16x8 a[9];
      const unsigned short* wp = wt + (((size_t)(cb * 9 + tap) * 9) << 9) + (lane << 3);
#pragma unroll
      for (int m = 0; m < 9; ++m) a[m] = *(const bf16x8*)(wp + (m << 9));
#pragma unroll
      for (int n = 0; n < 2; ++n) {
        int px = ((wave << 1) + n) * 16 + ln;
        int row = (px >> 6) + ky, cc = (px & 63) + kx;
        int e = ((row * 66 + cc) << 5) + ((kg ^ (cc & 3)) << 3);
        bf16x8 bv = *(const bf16x8*)&xs[e];
        __builtin_amdgcn_s_setprio(1);
#pragma unroll
        for (int m = 0; m < 9; ++m)
          acc[m][n] = __builtin_amdgcn_mfma_f32_16x16x32_bf16(a[m], bv, acc[m][n], 0, 0, 0);
        __builtin_amdgcn_s_setprio(0);
      }
    }
  }

  // epilogue: C/D col=lane&15 (px), row=(lane>>4)*4+r (co); pack pairs fp16
#pragma unroll
  for (int n = 0; n < 2; ++n) {
    int px = ((wave << 1) + n) * 16 + ln;
    int y = y0 + (px >> 6), x = px & 63;
#pragma unroll
    for (int m = 0; m < 9; ++m) {
      int cob = m * 16 + (kg << 2);
#pragma unroll
      for (int rr = 0; rr < 4; rr += 2) {
        unsigned v = packh2(acc[m][n][rr] + bias[cob + rr],
                            acc[m][n][rr + 1] + bias[cob + rr + 1]);
        offp[(((size_t)(b * 72 + ((cob + rr) >> 1))) << 12) + (y << 6) + x] = v;
      }
    }
  }
}

// ---------------------------------------------------------------------------
// Kernel 3: deformable conv via MFMA — r18-proven version EXACTLY (best
// measured: 171.5us). 512 thr, 8 waves = 2M x 4N, XCD swizzle,
// tap-in-register geometry, x-pair fold, full-issue packed-fp16 gather,
// colsT[px][202] f16, tri-buffered A with counted vmcnt(2), T5 setprio.
// (r19's cross-group register-held gather REVERTED: +6MB spill traffic.)
// ---------------------------------------------------------------------------
__global__ __launch_bounds__(512, 4) void dcn_mfma(
    const _Float16* __restrict__ fuB, const unsigned* __restrict__ offp,
    const _Float16* __restrict__ wt, const float* __restrict__ bias,
    float* __restrict__ out) {
  const int bid = (blockIdx.x & 7) * 128 + (blockIdx.x >> 3);  // XCD swizzle
  const int b = bid >> 6, h = bid & 63;
  const int tid = threadIdx.x;
  const int wave = tid >> 6, lane = tid & 63;
  const int kg = lane >> 4, ln = lane & 15;
  const int wm = wave >> 2, wn = wave & 3;   // M-half, N-tile
  const int px = (wn << 4) + ln;             // this wave's pixel (n index)

  __shared__ __align__(16) unsigned short colsT[64 * 202];// [px][r pad 202], f16
  __shared__ __align__(16) _Float16 wl[3][8192];          // A tri-buf, 3x16KB

  f32x4 acc[8];
#pragma unroll
  for (int m = 0; m < 8; ++m) acc[m] = {0.f, 0.f, 0.f, 0.f};

  // zero K-pad region r in [162,192) once (15 u32 per px) — MFMA-safe pad
  for (int i = tid; i < 64 * 15; i += 512) {
    int p = i / 15, d = i - p * 15;
    *(unsigned*)&colsT[p * 202 + 162 + 2 * d] = 0u;
  }

  // prologue: stage A chunk t=0 into buffer 0 (16 rows of 1KB, 2 per wave)
  {
    const _Float16* src = wt + (wave * 2) * 512 + lane * 8;
#pragma unroll
    for (int j = 0; j < 2; ++j)
      gload_lds16(src + j * 512, &wl[0][(wave * 2 + j) * 512]);
  }

  // geometry for (group, tap, pixel p), x-corner-pair folded (r11-proven):
  //   gg.x = iL0 | iL1<<16 ; gg.z = (wl0,wh0) f16 pair ; gg.w = (wl1,wh1)
  auto make_geo = [&](int gg_, int tap, int p) -> uint4 {
    int ky = tap / 3, kx = tap - ky * 3;
    unsigned op = offp[(((size_t)(b * 72 + gg_ * 9 + tap)) << 12) + (h << 6) + p];
    float oy = h2f_lo(op), ox = h2f_hi(op);
    float py = (float)(h - 1 + ky) + oy;
    float pxs = (float)(p - 1 + kx) + ox;
    float y0f = floorf(py), x0f = floorf(pxs);
    int y0 = (int)y0f, x0 = (int)x0f;
    float fy = py - y0f, fx = pxs - x0f;
    float vy0 = (y0 >= 0 && y0 < 64) ? 1.f : 0.f;
    float vy1 = (y0 + 1 >= 0 && y0 + 1 < 64) ? 1.f : 0.f;
    float vx0 = (x0 >= 0 && x0 < 64) ? 1.f : 0.f;
    float vx1 = (x0 + 1 >= 0 && x0 + 1 < 64) ? 1.f : 0.f;
    float a0 = (1.f - fx) * vx0;
    float a1 = fx * vx1;
    float wlo = (x0 == -1) ? a1 : (x0 == 63 ? 0.f : a0);
    float whi = (x0 == 63) ? a0 : (x0 == -1 ? 0.f : a1);
    int xL = min(max(x0, 0), 62);
    int yc0 = min(max(y0, 0), 63), yc1 = min(max(y0 + 1, 0), 63);
    float cy0 = (1.f - fy) * vy0, cy1 = fy * vy1;
    uint4 r;
    r.x = (unsigned)((yc0 << 6) + xL) | ((unsigned)((yc1 << 6) + xL) << 16);
    r.y = 0u;
    r.z = packh2(cy0 * wlo, cy0 * whi);
    r.w = packh2(cy1 * wlo, cy1 * whi);
    return r;
  };

  int tg = 0, cur = 0;  // global K-step, tri-buffer index (cur == tg % 3)
  for (int g = 0; g < OFFG; ++g) {
    __syncthreads();  // prev group's colsT readers done

    // ---- phase 1: wave w computes tap-w AND tap-8 geometry in registers
    uint4 gg = make_geo(g, wave, lane);
    uint4 g8 = make_geo(g, 8, lane);

    // ---- phase 2: gather, FULL-ISSUE; packed fp16 sample math
    const _Float16* gbase = fuB + (((size_t)(b * C_IN + g * CG)) << 12);
    {
      const int iL0 = gg.x & 0xFFFFu, iL1 = gg.x >> 16;
      const f16x2 w0 = __builtin_bit_cast(f16x2, gg.z);
      const f16x2 w1 = __builtin_bit_cast(f16x2, gg.w);
      const int j0 = g8.x & 0xFFFFu, j1 = g8.x >> 16;
      const f16x2 u0 = __builtin_bit_cast(f16x2, g8.z);
      const f16x2 u1 = __builtin_bit_cast(f16x2, g8.w);
      const int n8 = (wave < 2) ? 3 : 2;

      unsigned d0[18], d1[18], e0[3], e1[3];
#pragma unroll
      for (int u = 0; u < 18; ++u) {          // 36 independent 4B loads
        const _Float16* pl = gbase + ((size_t)u << 12);
        __builtin_memcpy(&d0[u], pl + iL0, 4);   // f16 pair (xL, xL+1)
        __builtin_memcpy(&d1[u], pl + iL1, 4);
      }
#pragma unroll
      for (int u = 0; u < 3; ++u) {           // up to 6 tap-8 loads
        if (u < n8) {
          const _Float16* pl = gbase + ((size_t)(wave + 8 * u) << 12);
          __builtin_memcpy(&e0[u], pl + j0, 4);
          __builtin_memcpy(&e1[u], pl + j1, 4);
        }
      }
#pragma unroll
      for (int u = 0; u < 18; ++u) {
        f16x2 sp = __builtin_bit_cast(f16x2, d0[u]) * w0 +
                   __builtin_bit_cast(f16x2, d1[u]) * w1;   // pk_mul + pk_fma
        _Float16 s = sp[0] + sp[1];
        colsT[lane * 202 + u * 9 + wave] = __builtin_bit_cast(unsigned short, s);
      }
#pragma unroll
      for (int u = 0; u < 3; ++u) {
        if (u < n8) {
          f16x2 sp = __builtin_bit_cast(f16x2, e0[u]) * u0 +
                     __builtin_bit_cast(f16x2, e1[u]) * u1;
          _Float16 s = sp[0] + sp[1];
          colsT[lane * 202 + (wave + 8 * u) * 9 + 8] =
              __builtin_bit_cast(unsigned short, s);
        }
      }
    }
    __syncthreads();  // colsT ready (full drain; also drains stage(tg))

    // ---- phase 3: 6 MFMA K-steps; counted-vmcnt tri-buffer staging (T4)
    for (int ks = 0; ks < 6; ++ks, ++tg) {
      // B fragment: 4 x ds_read_b32 (odd-dword row stride, conflict-free)
      int cbase = px * 202 + ks * 32 + (kg << 3);
      u32x4 bu;
      bu[0] = *(const unsigned*)&colsT[cbase];
      bu[1] = *(const unsigned*)&colsT[cbase + 2];
      bu[2] = *(const unsigned*)&colsT[cbase + 4];
      bu[3] = *(const unsigned*)&colsT[cbase + 6];
      f16x8 bv = __builtin_bit_cast(f16x8, bu);

      int nxt = cur + 1;
      if (nxt == 3) nxt = 0;
      if (tg < 47) {
        const _Float16* src =
            wt + (size_t)(tg + 1) * 8192 + (wave * 2) * 512 + lane * 8;
        _Float16* dst = wl[nxt];
#pragma unroll
        for (int j = 0; j < 2; ++j)
          gload_lds16(src + j * 512, dst + (wave * 2 + j) * 512);
        asm volatile("s_waitcnt vmcnt(2)" ::: "memory");
      } else {
        asm volatile("s_waitcnt vmcnt(0)" ::: "memory");
      }
      __builtin_amdgcn_s_barrier();

      // 8 MFMAs: this wave's M-half against its B fragment (T5 setprio)
      const _Float16* wbuf = wl[cur] + (wm * 8) * 512 + lane * 8;
      __builtin_amdgcn_s_setprio(1);
#pragma unroll
      for (int j = 0; j < 8; ++j) {
        f16x8 av = *(const f16x8*)(wbuf + j * 512);
        acc[j] = __builtin_amdgcn_mfma_f32_16x16x32_f16(av, bv, acc[j], 0, 0, 0);
      }
      __builtin_amdgcn_s_setprio(0);
      cur = nxt;
    }
  }

  // ---- epilogue: bias + SiLU.  C/D: col(px)=lane&15, row=kg*4+r
#pragma unroll
  for (int j = 0; j < 8; ++j) {
    int cob = (wm * 8 + j) * 16 + (kg << 2);
#pragma unroll
    for (int r = 0; r < 4; ++r) {
      float y = acc[j][r] + bias[cob + r];
      out[(((size_t)(b * C_OUT + cob + r)) << 12) + (h << 6) + px] =
          y / (1.f + expf(-y));
    }
  }
}

// ---------------------------------------------------------------------------
extern "C" void kernel_launch(void* const* d_in, const int* in_sizes, int n_in,
                              void* d_out, int out_size, void* d_ws, size_t ws_size,
                              hipStream_t stream) {
  const float* feat_arm = (const float*)d_in[0];
  const float* feat_up  = (const float*)d_in[1];
  const float* off_w    = (const float*)d_in[2];
  const float* off_b    = (const float*)d_in[3];
  const float* dcn_w    = (const float*)d_in[4];
  const float* dcn_b    = (const float*)d_in[5];
  float* out = (float*)d_out;

  // ws layout (identical sizes to rounds 12-19):
  _Float16* fuB = (_Float16*)d_ws;                        // FUB_ELEMS f16
  unsigned* offp = (unsigned*)(fuB + FUB_ELEMS);          // OFFP_ELEMS u32
  unsigned short* wo = (unsigned short*)(offp + OFFP_ELEMS);
  _Float16* wd = (_Float16*)(wo + WOFF_PACK);

  prep<<<(WDCN_PACK + 255) / 256, 256, 0, stream>>>(off_w, dcn_w, wo, wd);
  offs_conv_mfma<<<BN * 32, 256, 0, stream>>>(feat_arm, feat_up, wo, off_b, offp, fuB);
  dcn_mfma<<<BN * 64, 512, 0, stream>>>(fuB, offp, wd, dcn_b, out);
}